// Round 2
// baseline (2641.559 us; speedup 1.0000x reference)
//
#include <hip/hip_runtime.h>

#define NN 2048
#define BB 8
#define NITER 50
#define NBAND 64              // 32-row band-groups per batch (64*32 = 2048)
#define ROWS_PER_WAVE 8
#define WPB 4                 // waves per block

__device__ __forceinline__ float eps_f()      { return 0.01f; }
__device__ __forceinline__ float inv_eps_f()  { return 100.0f; }
// 0.01f * (-logf(2048.f))
__device__ __forceinline__ float eps_logmu_f(){ return -0.0762461898616f; }

// online LSE combine of (max, sum-of-exps-rel-to-max) pairs; args are in
// x-space (the LSE argument is x*100)
__device__ __forceinline__ void lse_combine(float& m, float& s, float om, float os) {
    float M = fmaxf(m, om);
    s = s * __expf((m - M) * inv_eps_f()) + os * __expf((om - M) * inv_eps_f());
    m = M;
}

// accumulate a single new value x into (m, s)
__device__ __forceinline__ void colacc(float& m, float& s, float x) {
    float M = fmaxf(m, x);
    s = s * __expf((m - M) * inv_eps_f()) + __expf((x - M) * inv_eps_f());
    m = M;
}

// ---------------- init: zero v ----------------
__global__ __launch_bounds__(256) void k_init(float* __restrict__ v) {
    int idx = blockIdx.x * 256 + threadIdx.x;
    if (idx < BB * NN) v[idx] = 0.0f;
}

// ---------------- fused iteration: one pass over c ----------------
// Per block: batch b, band of 32 rows. Wave w handles 8 rows.
// For each row: row-LSE of (c+v) -> u_i (shuffle reduce), write u, then fold
// x = c + u_i into per-lane column accumulators (lane owns cols q*256+lane*4+e).
// End of band: LDS-combine the 4 waves' column accumulators -> one partial/col.
__global__ __launch_bounds__(256, 2) void k_iter(const float* __restrict__ c,
                                                 const float* __restrict__ v,
                                                 float* __restrict__ u,
                                                 float* __restrict__ pm,
                                                 float* __restrict__ ps) {
    __shared__ float lds_v[NN];
    __shared__ float lds_m[WPB][NN];
    __shared__ float lds_s[WPB][NN];

    int b    = blockIdx.x >> 6;       // / NBAND
    int band = blockIdx.x & 63;
    int t    = threadIdx.x;
    int wave = t >> 6;
    int lane = t & 63;

    // stage v[b][:] into LDS (coalesced float4)
    const float4* vg = (const float4*)(v + b * NN);
    ((float4*)lds_v)[t]       = vg[t];
    ((float4*)lds_v)[t + 256] = vg[t + 256];
    __syncthreads();

    // my column slice of v: col(q,e) = q*256 + lane*4 + e
    float4 vv[8];
#pragma unroll
    for (int q = 0; q < 8; ++q) vv[q] = *(const float4*)(lds_v + q * 256 + lane * 4);

    // per-lane column accumulators
    float4 cm[8], cs[8];
#pragma unroll
    for (int q = 0; q < 8; ++q) {
        cm[q] = make_float4(-INFINITY, -INFINITY, -INFINITY, -INFINITY);
        cs[q] = make_float4(0.f, 0.f, 0.f, 0.f);
    }

    int row0 = band * (WPB * ROWS_PER_WAVE) + wave * ROWS_PER_WAVE;
    const float* cb = c + ((size_t)b * NN + row0) * NN;

    for (int r = 0; r < ROWS_PER_WAVE; ++r) {
        const float4* crow = (const float4*)(cb + (size_t)r * NN);
        float4 cr[8];
#pragma unroll
        for (int q = 0; q < 8; ++q) cr[q] = crow[q * 64 + lane];

        // ---- row online LSE of (c+v) ----
        float m = -INFINITY, s = 0.0f;
#pragma unroll
        for (int q = 0; q < 8; ++q) {
            float x0 = cr[q].x + vv[q].x;
            float x1 = cr[q].y + vv[q].y;
            float x2 = cr[q].z + vv[q].z;
            float x3 = cr[q].w + vv[q].w;
            float lm = fmaxf(fmaxf(x0, x1), fmaxf(x2, x3));
            float M  = fmaxf(m, lm);
            s = s * __expf((m - M) * inv_eps_f())
              + __expf((x0 - M) * inv_eps_f()) + __expf((x1 - M) * inv_eps_f())
              + __expf((x2 - M) * inv_eps_f()) + __expf((x3 - M) * inv_eps_f());
            m = M;
        }
        // wave butterfly reduce (all 64 lanes end with the row LSE)
#pragma unroll
        for (int off = 32; off; off >>= 1) {
            float om = __shfl_xor(m, off, 64);
            float os = __shfl_xor(s, off, 64);
            lse_combine(m, s, om, os);
        }
        float ui = eps_logmu_f() - m - eps_f() * __logf(s);
        if (lane == 0) u[b * NN + row0 + r] = ui;

        // ---- column accumulate: x = c + u_i ----
#pragma unroll
        for (int q = 0; q < 8; ++q) {
            colacc(cm[q].x, cs[q].x, cr[q].x + ui);
            colacc(cm[q].y, cs[q].y, cr[q].y + ui);
            colacc(cm[q].z, cs[q].z, cr[q].z + ui);
            colacc(cm[q].w, cs[q].w, cr[q].w + ui);
        }
    }

    // dump per-wave accumulators to LDS (contiguous b128 per wave -> no conflicts)
#pragma unroll
    for (int q = 0; q < 8; ++q) {
        int col = q * 256 + lane * 4;
        *(float4*)(&lds_m[wave][col]) = cm[q];
        *(float4*)(&lds_s[wave][col]) = cs[q];
    }
    __syncthreads();

    // combine 4 waves -> one partial per column; thread t handles cols k*256+t
    size_t obase = (size_t)(b * NBAND + band) * NN;
#pragma unroll
    for (int k = 0; k < 8; ++k) {
        int col = k * 256 + t;
        float m = lds_m[0][col], s = lds_s[0][col];
#pragma unroll
        for (int w = 1; w < WPB; ++w) lse_combine(m, s, lds_m[w][col], lds_s[w][col]);
        pm[obase + col] = m;
        ps[obase + col] = s;
    }
}

// ---------------- combine band partials -> v ----------------
__global__ __launch_bounds__(256) void k_v_combine(const float* __restrict__ pm,
                                                   const float* __restrict__ ps,
                                                   float* __restrict__ v) {
    int idx = blockIdx.x * 256 + threadIdx.x;   // b*NN + j
    int b = idx >> 11;
    int j = idx & (NN - 1);
    float m = -INFINITY, s = 0.0f;
    for (int r = 0; r < NBAND; ++r) {
        size_t o = (size_t)(b * NBAND + r) * NN + j;
        lse_combine(m, s, pm[o], ps[o]);
    }
    float val = eps_logmu_f() - m - eps_f() * __logf(s);
    if (val > 9e8f) val = 0.0f;   // reference's huge-value clamp (never fires)
    v[idx] = val;
}

// ---------------- finalize: pi = exp((c+u+v)*100), negc = -c ----------------
__global__ __launch_bounds__(256) void k_final(const float* __restrict__ c,
                                               const float* __restrict__ u,
                                               const float* __restrict__ v,
                                               float* __restrict__ pi,
                                               float* __restrict__ negc) {
    unsigned q = blockIdx.x * 256 + threadIdx.x;     // float4 index
    unsigned e = q * 4;
    unsigned b = e >> 22;
    unsigned rem = e & (NN * NN - 1);
    unsigned i = rem >> 11;
    unsigned j = rem & (NN - 1);

    float4 cc = ((const float4*)c)[q];
    float ui = u[b * NN + i];
    float4 vv = *(const float4*)(v + b * NN + j);

    float4 p;
    p.x = __expf((cc.x + ui + vv.x) * inv_eps_f());
    p.y = __expf((cc.y + ui + vv.y) * inv_eps_f());
    p.z = __expf((cc.z + ui + vv.z) * inv_eps_f());
    p.w = __expf((cc.w + ui + vv.w) * inv_eps_f());
    ((float4*)pi)[q] = p;

    float4 nc = { -cc.x, -cc.y, -cc.z, -cc.w };
    ((float4*)negc)[q] = nc;
}

// ---------------- copy u, v to output ----------------
__global__ __launch_bounds__(256) void k_uv_out(const float* __restrict__ u,
                                                const float* __restrict__ v,
                                                float* __restrict__ ou,
                                                float* __restrict__ ov) {
    int idx = blockIdx.x * 256 + threadIdx.x;
    if (idx < BB * NN) { ou[idx] = u[idx]; ov[idx] = v[idx]; }
}

extern "C" void kernel_launch(void* const* d_in, const int* in_sizes, int n_in,
                              void* d_out, int out_size, void* d_ws, size_t ws_size,
                              hipStream_t stream) {
    const float* c = (const float*)d_in[0];
    float* out  = (float*)d_out;
    float* pi   = out;
    float* negc = out + (size_t)BB * NN * NN;
    float* ou   = out + 2 * (size_t)BB * NN * NN;
    float* ov   = ou + BB * NN;

    float* ws = (float*)d_ws;
    float* u  = ws;                         // BB*NN
    float* v  = ws + BB * NN;               // BB*NN
    float* pm = ws + 2 * BB * NN;           // BB*NBAND*NN
    float* ps = pm + (size_t)BB * NBAND * NN;

    k_init<<<(BB * NN) / 256, 256, 0, stream>>>(v);

    for (int it = 0; it < NITER; ++it) {
        k_iter<<<BB * NBAND, 256, 0, stream>>>(c, v, u, pm, ps);
        k_v_combine<<<(BB * NN) / 256, 256, 0, stream>>>(pm, ps, v);
    }

    unsigned n4 = (unsigned)((size_t)BB * NN * NN / 4);
    k_final<<<n4 / 256, 256, 0, stream>>>(c, u, v, pi, negc);
    k_uv_out<<<(BB * NN) / 256, 256, 0, stream>>>(u, v, ou, ov);
}